// Round 18
// baseline (133.189 us; speedup 1.0000x reference)
//
#include <hip/hip_runtime.h>
#include <hip/hip_fp16.h>
#include <stdint.h>

typedef _Float16 f16;
typedef _Float16 half8  __attribute__((ext_vector_type(8)));
typedef _Float16 half4v __attribute__((ext_vector_type(4)));
typedef float    f32x4  __attribute__((ext_vector_type(4)));

#define NBATCH 4
#define SEQ    4096
#define DMODEL 256
#define DHEAD  64
#define NQKV   192
// q pre-scale: 1/sqrt(64) * log2(e) -> scores arrive in log2 domain; exp = exp2
#define QSCALE 0.180336880f

// ---------------------------------------------------------------------------
// Kernel A (R14/R15, verified): qkv via MFMA (fp16 in, fp32 acc); q pre-scale
// includes log2(e). Tail emits W_out^T fp16.
// ---------------------------------------------------------------------------
#define XSP 272
#define WQP 40

__device__ __forceinline__ void stage_w(const float* __restrict__ Wq,
                                        f16* dst, int kk, int t) {
#pragma unroll
  for (int uu = 0; uu < 3; ++uu) {
    const int u = uu * 256 + t;       // 0..767 16B-units
    const int n = u >> 2;             // 0..191
    const int kc8 = u & 3;
    const int k0 = kk * 32 + kc8 * 8;
    half8 hv;
#pragma unroll
    for (int e = 0; e < 8; ++e) hv[e] = (f16)Wq[(size_t)(k0 + e) * NQKV + n];
    *(half8*)(dst + n * WQP + kc8 * 8) = hv;
  }
}

__global__ __launch_bounds__(256) void qkv_mfma(
    const float* __restrict__ x, const float* __restrict__ Wq,
    const float* __restrict__ bq, const float* __restrict__ Wo,
    f16* __restrict__ qh, f16* __restrict__ kh, f16* __restrict__ vt,
    f16* __restrict__ wt)
{
  __shared__ f16 xs[64 * XSP];          // 34816 B
  __shared__ f16 wql[2][192 * WQP];     // 30720 B  (total 64 KB)
  const int t = threadIdx.x;
  const int w = t >> 6;
  const int l = t & 63;
  const int qr = l & 15;
  const int g  = l >> 4;
  const int row0 = blockIdx.x * 64;
  const int bi   = row0 >> 12;
  const int seqb = row0 & (SEQ - 1);

  // ---- stage x tile (fp32 -> fp16) ----
#pragma unroll
  for (int j = 0; j < 16; ++j) {
    const int li = j * 256 + t;         // float4-units
    const int r = li >> 6, c4 = (li & 63) * 4;
    float4 v4 = *(const float4*)(x + (size_t)(row0 + r) * DMODEL + c4);
    half4v h = {(f16)v4.x, (f16)v4.y, (f16)v4.z, (f16)v4.w};
    *(half4v*)(xs + r * XSP + c4) = h;
  }
  stage_w(Wq, wql[0], 0, t);
  __syncthreads();

  f32x4 acc[12];
#pragma unroll
  for (int i = 0; i < 12; ++i) acc[i] = (f32x4){0.f, 0.f, 0.f, 0.f};

  for (int kk = 0; kk < 8; ++kk) {
    if (kk < 7) stage_w(Wq, wql[(kk + 1) & 1], kk + 1, t);
    const f16* wb = wql[kk & 1];
    const half8 xa = *(const half8*)(xs + (w * 16 + qr) * XSP + kk * 32 + 8 * g);
#pragma unroll
    for (int nt = 0; nt < 12; ++nt) {
      const half8 wf = *(const half8*)(wb + (nt * 16 + qr) * WQP + 8 * g);
      if (nt < 8) acc[nt] = __builtin_amdgcn_mfma_f32_16x16x32_f16(wf, xa, acc[nt], 0, 0, 0);
      else        acc[nt] = __builtin_amdgcn_mfma_f32_16x16x32_f16(xa, wf, acc[nt], 0, 0, 0);
    }
    __syncthreads();
  }

  // ---- epilogue: bias, q-scale (incl. log2e), fp16 stores ----
  const size_t grow = (size_t)row0 + w * 16 + qr;   // global row (q/k paths)
#pragma unroll
  for (int nt = 0; nt < 4; ++nt) {                  // q: D[d=4g+r][seq=qr]
    float4 b4 = *(const float4*)(bq + nt * 16 + 4 * g);
    half4v hv = {(f16)((acc[nt][0] + b4.x) * QSCALE),
                 (f16)((acc[nt][1] + b4.y) * QSCALE),
                 (f16)((acc[nt][2] + b4.z) * QSCALE),
                 (f16)((acc[nt][3] + b4.w) * QSCALE)};
    *(half4v*)(qh + grow * DHEAD + nt * 16 + 4 * g) = hv;
  }
#pragma unroll
  for (int nt = 4; nt < 8; ++nt) {                  // k
    float4 b4 = *(const float4*)(bq + 64 + (nt - 4) * 16 + 4 * g);
    half4v hv = {(f16)(acc[nt][0] + b4.x), (f16)(acc[nt][1] + b4.y),
                 (f16)(acc[nt][2] + b4.z), (f16)(acc[nt][3] + b4.w)};
    *(half4v*)(kh + grow * DHEAD + (nt - 4) * 16 + 4 * g) = hv;
  }
#pragma unroll
  for (int nt = 8; nt < 12; ++nt) {                 // v: D[seq=4g+r][d=qr]
    const int d = (nt - 8) * 16 + qr;
    const float bv = bq[128 + d];
    half4v hv = {(f16)(acc[nt][0] + bv), (f16)(acc[nt][1] + bv),
                 (f16)(acc[nt][2] + bv), (f16)(acc[nt][3] + bv)};
    *(half4v*)(vt + (size_t)bi * DHEAD * SEQ + (size_t)d * SEQ
               + seqb + w * 16 + 4 * g) = hv;
  }
  // ---- tail: blocks 0..15 emit W_out^T fp16 (wt[c][k]) ----
  if (blockIdx.x < 16) {
    const int gid = blockIdx.x * 256 + t;   // 0..4095
    const int c = gid & 255;
    const int k0 = (gid >> 8) * 4;          // 0..60
    half4v wv = {(f16)Wo[(size_t)(k0 + 0) * DMODEL + c],
                 (f16)Wo[(size_t)(k0 + 1) * DMODEL + c],
                 (f16)Wo[(size_t)(k0 + 2) * DMODEL + c],
                 (f16)Wo[(size_t)(k0 + 3) * DMODEL + c]};
    *(half4v*)(wt + (size_t)c * DHEAD + k0) = wv;
  }
}

// ---------------------------------------------------------------------------
// Kernel B: fused scores -> threshold -> masked softmax -> PV -> OUT PROJ.
// R18 change: QK^T K-fragments loaded DIRECTLY global->register (the staged
// LDS slot XOR cancels: consumed data = global octets g and 4+g of row rowk).
// Removes ALL QK LDS traffic (4KB read + 4KB DMA write per wave-chunk) —
// the post-mortem identified the LDS data path (reads + global_load_lds
// writes) as the saturated pipe. Register dbuf, distance-1, fully unrolled
// (compile-time indices). V path / PV pipeline unchanged from R15-verified.
// ---------------------------------------------------------------------------
#define WAVES  8
#define CHUNK  32
#define NCHUNK 16
#define BUFH   2048    // halves per buffer (4 KB = 32 rows x 64 halves)

typedef __attribute__((address_space(3))) f16 as3_f16;
typedef __attribute__((address_space(1))) const f16 as1_f16;

__device__ __forceinline__ void gll16(const f16* g, f16* l) {
  __builtin_amdgcn_global_load_lds((as1_f16*)g, (as3_f16*)l, 16, 0, 0);
}

#define SCHED_PIN __builtin_amdgcn_sched_barrier(0)
#define WAITVM4 do { asm volatile("s_waitcnt vmcnt(4)" ::: "memory"); \
                     __builtin_amdgcn_sched_barrier(0); } while (0)
#define WAITVM0 do { asm volatile("s_waitcnt vmcnt(0)" ::: "memory"); \
                     __builtin_amdgcn_sched_barrier(0); } while (0)

// V chunk -> LDS rows = d&31 (128 B), slots 0..3 = d<32, 4..7 = d>=32, XOR r&7
__device__ __forceinline__ void stage_v(const f16* vchunk, f16* buf, int l) {
#pragma unroll
  for (int i = 0; i < 4; ++i) {
    const int r = i * 8 + (l >> 3);
    const int jj = (l & 7) ^ (r & 7);
    const int d = ((jj >> 2) << 5) + r;
    const int kb = jj & 3;
    gll16(vchunk + (size_t)d * SEQ + kb * 8, buf + i * 512);
  }
}

__global__ __launch_bounds__(512) void attn_fused(
    const f16* __restrict__ qh, const f16* __restrict__ kh,
    const f16* __restrict__ vt, const f16* __restrict__ wt,
    const float* __restrict__ bo, float* __restrict__ out)
{
  __shared__ f16 stage[WAVES][2 * BUFH];     // 64 KB: per-wave double buffer (V)
  __shared__ float selbuf[WAVES][16];        // z cross-wave reduce only
  __shared__ float zrow[16];
  __shared__ float obuf[16 * 68];            // 4.35 KB: O rows (post-division)

  const int tid = threadIdx.x;
  const int w = tid >> 6;
  const int l = tid & 63;
  const int qr = l & 15;
  const int g  = l >> 4;
  const int bi = blockIdx.x >> 8;
  const int rb = blockIdx.x & 255;
  const size_t qrow0  = (size_t)bi * SEQ + (size_t)rb * 16;
  const size_t kvbase = (size_t)bi * SEQ * DHEAD;
  const int key0 = w * (CHUNK * NCHUNK);

  f16* const mybuf = &stage[w][0];

  // Q fragments (B operand), q pre-scaled by QSCALE in qh.
  half8 qf0, qf1;
  {
    const f16* qp = qh + (qrow0 + qr) * DHEAD;
    qf0 = *(const half8*)(qp + 8 * g);
    qf1 = *(const half8*)(qp + 32 + 8 * g);
  }

  half4v P[2 * NCHUNK];   // P[2kc+kt][r] = S[qr][32kc + 8g + 4kt + r] (log2 dom.)
  float mn = 1e30f, mx = -1e30f;

  // ---- QK^T: K frags DIRECT global->register, register dbuf, dist-1 ----
  // lane base: permuted key row rowk(kt)=8*(qr>>2)+4*kt+(qr&3); octets g, 4+g.
  const f16* lane0 = kh + kvbase + (size_t)(key0 + 8 * (qr >> 2) + (qr & 3)) * DHEAD + 8 * g;
  half8 ka[2][4];   // [buf][kt*2+part]; indices compile-time (full unroll)
  ka[0][0] = *(const half8*)(lane0);
  ka[0][1] = *(const half8*)(lane0 + 32);
  ka[0][2] = *(const half8*)(lane0 + 4 * DHEAD);
  ka[0][3] = *(const half8*)(lane0 + 4 * DHEAD + 32);
#pragma unroll
  for (int kc = 0; kc < NCHUNK; ++kc) {
    const int cur = kc & 1;
    if (kc + 1 < NCHUNK) {
      const f16* np = lane0 + (size_t)(kc + 1) * CHUNK * DHEAD;
      ka[cur ^ 1][0] = *(const half8*)(np);
      ka[cur ^ 1][1] = *(const half8*)(np + 32);
      ka[cur ^ 1][2] = *(const half8*)(np + 4 * DHEAD);
      ka[cur ^ 1][3] = *(const half8*)(np + 4 * DHEAD + 32);
    }
#pragma unroll
    for (int kt = 0; kt < 2; ++kt) {
      f32x4 c = {0.f, 0.f, 0.f, 0.f};
      c = __builtin_amdgcn_mfma_f32_16x16x32_f16(ka[cur][kt * 2 + 0], qf0, c, 0, 0, 0);
      c = __builtin_amdgcn_mfma_f32_16x16x32_f16(ka[cur][kt * 2 + 1], qf1, c, 0, 0, 0);
      mn = fminf(mn, fminf(fminf(c[0], c[1]), fminf(c[2], c[3])));
      mx = fmaxf(mx, fmaxf(fmaxf(c[0], c[1]), fmaxf(c[2], c[3])));
      P[kc * 2 + kt] = (half4v){(f16)c[0], (f16)c[1], (f16)c[2], (f16)c[3]};
    }
  }

  // ---- prefetch V chunks 0/1 into LDS now (hidden under selection+exp) ----
  const f16* vchunk0 = vt + (size_t)bi * DHEAD * SEQ + key0;
  stage_v(vchunk0, mybuf, l);
  stage_v(vchunk0 + 32, mybuf + BUFH, l);

  // ---- WAVE-LOCAL selection: row min/max across the row's 4 lanes ----
  mn = fminf(mn, __shfl_xor(mn, 16, 64));
  mn = fminf(mn, __shfl_xor(mn, 32, 64));
  mx = fmaxf(mx, __shfl_xor(mx, 16, 64));
  mx = fmaxf(mx, __shfl_xor(mx, 32, 64));
  float lo = mn, hi = mx;

  // ---- wave-local bisection: 128 samples/row (32/lane), target 64 ----
#pragma unroll
  for (int it = 0; it < 10; ++it) {
    const float tm = 0.5f * (lo + hi);
    const f16 th = (f16)tm;
    int cnt = 0;
#pragma unroll
    for (int j = 0; j < 2 * NCHUNK; j += 4) {
      half4v s = P[j];
      cnt += (s[0] >= th) + (s[1] >= th) + (s[2] >= th) + (s[3] >= th);
    }
    cnt += __shfl_xor(cnt, 16, 64);
    cnt += __shfl_xor(cnt, 32, 64);
    if (cnt >= 64) lo = tm; else hi = tm;
  }
  const float thr = lo;

  // ---- exp2 in place (scores already in log2 domain; masked -> 1) ----
  float z = 0.f;
#pragma unroll
  for (int j = 0; j < 2 * NCHUNK; ++j) {
    half4v s = P[j];
    float p0 = (float)s[0], p1 = (float)s[1], p2 = (float)s[2], p3 = (float)s[3];
    p0 = (p0 >= thr) ? exp2f(p0) : 1.f;
    p1 = (p1 >= thr) ? exp2f(p1) : 1.f;
    p2 = (p2 >= thr) ? exp2f(p2) : 1.f;
    p3 = (p3 >= thr) ? exp2f(p3) : 1.f;
    z += (p0 + p1) + (p2 + p3);
    P[j] = (half4v){(f16)p0, (f16)p1, (f16)p2, (f16)p3};
  }
  z += __shfl_xor(z, 16, 64);
  z += __shfl_xor(z, 32, 64);
  if (l < 16) selbuf[w][l] = z;
  __syncthreads();
  if (w == 0 && l < 16) {
    float t2 = 0.f;
#pragma unroll
    for (int j = 0; j < WAVES; ++j) t2 += selbuf[j][l];
    zrow[l] = t2;   // consumed after the post-PV barrier
  }

  // ---- PV: O^T = V^T P^T; A = V^T (b128 LDS reads), B = P register concat ----
  f32x4 acc[4];
#pragma unroll
  for (int p = 0; p < 4; ++p) acc[p] = (f32x4){0.f, 0.f, 0.f, 0.f};

#pragma unroll
  for (int kc = 0; kc < NCHUNK; ++kc) {
    if (kc < NCHUNK - 1) { WAITVM4; } else { WAITVM0; }
    const f16* bufp = mybuf + (kc & 1) * BUFH;
    const half8 pb = __builtin_shufflevector(P[kc * 2], P[kc * 2 + 1],
                                             0, 1, 2, 3, 4, 5, 6, 7);
#pragma unroll
    for (int pnl = 0; pnl < 4; ++pnl) {
      const int d = 16 * pnl + qr;
      const int r = d & 31;
      const int j = (((d >> 5) << 2) + g) ^ (r & 7);
      half8 va = *(const half8*)(bufp + r * 64 + j * 8);
      acc[pnl] = __builtin_amdgcn_mfma_f32_16x16x32_f16(va, pb, acc[pnl], 0, 0, 0);
    }
    if (kc + 2 < NCHUNK) {
      SCHED_PIN;   // all reads of buf[kc&1] complete (in-order DS) before DMA
      stage_v(vchunk0 + (kc + 2) * 32, mybuf + (kc & 1) * BUFH, l);
    }
  }

  // ---- cross-wave reduce -> obuf (O/z), 68-pad rows ----
  float* red = (float*)mybuf;   // 16 rows x 68 floats = 4352 B per wave region
#pragma unroll
  for (int pnl = 0; pnl < 4; ++pnl)
    *(f32x4*)&red[qr * 68 + pnl * 16 + 4 * g] = acc[pnl];
  __syncthreads();
#pragma unroll
  for (int oo = 0; oo < 2; ++oo) {
    const int o = tid * 2 + oo;
    const int i = o >> 6, n = o & 63;
    float s = 0.f;
#pragma unroll
    for (int j = 0; j < WAVES; ++j) s += ((const float*)&stage[j][0])[i * 68 + n];
    obuf[i * 68 + n] = s / zrow[i];
  }
  __syncthreads();   // red reads done (stage reusable); obuf visible to all

  // ---- stage wt (W^T fp16) into stage[0..32KB]: wave w -> rows 32w..32w+31,
  // LDS linear, source block pre-XOR'd with (c&7) ----
  f16* const wl = &stage[0][0];
#pragma unroll
  for (int i = 0; i < 4; ++i) {
    const int c = (w * 4 + i) * 8 + (l >> 3);
    const int blk = (l & 7) ^ (c & 7);
    gll16(wt + (size_t)c * DHEAD + blk * 8, wl + (w * 4 + i) * 512);
  }
  WAITVM0;   // wave-local: wave w reads only rows it staged

  // ---- out = O @ W^T + bo via MFMA: wave w owns col tiles nt = 2w, 2w+1 ----
  half4v ofr[4];
#pragma unroll
  for (int pnl = 0; pnl < 4; ++pnl) {
    f32x4 o4 = *(const f32x4*)&obuf[qr * 68 + pnl * 16 + 4 * g];
    ofr[pnl] = (half4v){(f16)o4[0], (f16)o4[1], (f16)o4[2], (f16)o4[3]};
  }
#pragma unroll
  for (int nt2 = 0; nt2 < 2; ++nt2) {
    const int nt = w * 2 + nt2;
    const int c = 16 * nt + qr;             // output column
    const float bv = bo[c];
    f32x4 ao = {bv, bv, bv, bv};
#pragma unroll
    for (int pnl = 0; pnl < 4; ++pnl) {
      const int blk = 2 * pnl + (g >> 1);   // k-block = (16pnl+4g)>>3
      half4v wf = *(const half4v*)(wl + c * DHEAD + ((blk ^ (c & 7)) * 8) + (g & 1) * 4);
      ao = __builtin_amdgcn_mfma_f32_16x16x16f16(ofr[pnl], wf, ao, 0, 0, 0);
    }
    float* op = out + (qrow0 + 4 * g) * DMODEL + c;
#pragma unroll
    for (int r = 0; r < 4; ++r) op[r * DMODEL] = ao[r];
  }
}

// ---------------------------------------------------------------------------
extern "C" void kernel_launch(void* const* d_in, const int* in_sizes, int n_in,
                              void* d_out, int out_size, void* d_ws, size_t ws_size,
                              hipStream_t stream)
{
  (void)in_sizes; (void)n_in; (void)out_size; (void)ws_size;
  const float* x  = (const float*)d_in[0];
  const float* Wq = (const float*)d_in[1];
  const float* bq = (const float*)d_in[2];
  const float* Wo = (const float*)d_in[3];
  const float* bo = (const float*)d_in[4];
  float* out = (float*)d_out;
  char* ws = (char*)d_ws;
  f16* qh = (f16*)(ws);                              // 2 MB
  f16* kh = (f16*)(ws + (size_t)(2 << 20));          // 2 MB
  f16* vt = (f16*)(ws + (size_t)(4 << 20));          // 2 MB (transposed V)
  f16* wt = (f16*)(ws + (size_t)(6 << 20));          // 32 KB (W_out^T fp16)

  hipLaunchKernelGGL(qkv_mfma,   dim3(256),  dim3(256), 0, stream, x, Wq, bq, Wo, qh, kh, vt, wt);
  hipLaunchKernelGGL(attn_fused, dim3(1024), dim3(512), 0, stream, qh, kh, vt, wt, bo, out);
}

// Round 19
// 100.585 us; speedup vs baseline: 1.3241x; 1.3241x over previous
//
#include <hip/hip_runtime.h>
#include <hip/hip_fp16.h>
#include <stdint.h>

typedef _Float16 f16;
typedef _Float16 half8  __attribute__((ext_vector_type(8)));
typedef _Float16 half4v __attribute__((ext_vector_type(4)));
typedef float    f32x4  __attribute__((ext_vector_type(4)));

#define NBATCH 4
#define SEQ    4096
#define DMODEL 256
#define DHEAD  64
#define NQKV   192
// q pre-scale: 1/sqrt(64) * log2(e) -> scores arrive in log2 domain; exp = exp2
#define QSCALE 0.180336880f

// ---------------------------------------------------------------------------
// Kernel A (R14/R15, verified): qkv via MFMA (fp16 in, fp32 acc); q pre-scale
// includes log2(e). Tail emits W_out^T fp16.
// ---------------------------------------------------------------------------
#define XSP 272
#define WQP 40

__device__ __forceinline__ void stage_w(const float* __restrict__ Wq,
                                        f16* dst, int kk, int t) {
#pragma unroll
  for (int uu = 0; uu < 3; ++uu) {
    const int u = uu * 256 + t;       // 0..767 16B-units
    const int n = u >> 2;             // 0..191
    const int kc8 = u & 3;
    const int k0 = kk * 32 + kc8 * 8;
    half8 hv;
#pragma unroll
    for (int e = 0; e < 8; ++e) hv[e] = (f16)Wq[(size_t)(k0 + e) * NQKV + n];
    *(half8*)(dst + n * WQP + kc8 * 8) = hv;
  }
}

__global__ __launch_bounds__(256) void qkv_mfma(
    const float* __restrict__ x, const float* __restrict__ Wq,
    const float* __restrict__ bq, const float* __restrict__ Wo,
    f16* __restrict__ qh, f16* __restrict__ kh, f16* __restrict__ vt,
    f16* __restrict__ wt)
{
  __shared__ f16 xs[64 * XSP];          // 34816 B
  __shared__ f16 wql[2][192 * WQP];     // 30720 B  (total 64 KB)
  const int t = threadIdx.x;
  const int w = t >> 6;
  const int l = t & 63;
  const int qr = l & 15;
  const int g  = l >> 4;
  const int row0 = blockIdx.x * 64;
  const int bi   = row0 >> 12;
  const int seqb = row0 & (SEQ - 1);

  // ---- stage x tile (fp32 -> fp16) ----
#pragma unroll
  for (int j = 0; j < 16; ++j) {
    const int li = j * 256 + t;         // float4-units
    const int r = li >> 6, c4 = (li & 63) * 4;
    float4 v4 = *(const float4*)(x + (size_t)(row0 + r) * DMODEL + c4);
    half4v h = {(f16)v4.x, (f16)v4.y, (f16)v4.z, (f16)v4.w};
    *(half4v*)(xs + r * XSP + c4) = h;
  }
  stage_w(Wq, wql[0], 0, t);
  __syncthreads();

  f32x4 acc[12];
#pragma unroll
  for (int i = 0; i < 12; ++i) acc[i] = (f32x4){0.f, 0.f, 0.f, 0.f};

  for (int kk = 0; kk < 8; ++kk) {
    if (kk < 7) stage_w(Wq, wql[(kk + 1) & 1], kk + 1, t);
    const f16* wb = wql[kk & 1];
    const half8 xa = *(const half8*)(xs + (w * 16 + qr) * XSP + kk * 32 + 8 * g);
#pragma unroll
    for (int nt = 0; nt < 12; ++nt) {
      const half8 wf = *(const half8*)(wb + (nt * 16 + qr) * WQP + 8 * g);
      if (nt < 8) acc[nt] = __builtin_amdgcn_mfma_f32_16x16x32_f16(wf, xa, acc[nt], 0, 0, 0);
      else        acc[nt] = __builtin_amdgcn_mfma_f32_16x16x32_f16(xa, wf, acc[nt], 0, 0, 0);
    }
    __syncthreads();
  }

  // ---- epilogue: bias, q-scale (incl. log2e), fp16 stores ----
  const size_t grow = (size_t)row0 + w * 16 + qr;   // global row (q/k paths)
#pragma unroll
  for (int nt = 0; nt < 4; ++nt) {                  // q: D[d=4g+r][seq=qr]
    float4 b4 = *(const float4*)(bq + nt * 16 + 4 * g);
    half4v hv = {(f16)((acc[nt][0] + b4.x) * QSCALE),
                 (f16)((acc[nt][1] + b4.y) * QSCALE),
                 (f16)((acc[nt][2] + b4.z) * QSCALE),
                 (f16)((acc[nt][3] + b4.w) * QSCALE)};
    *(half4v*)(qh + grow * DHEAD + nt * 16 + 4 * g) = hv;
  }
#pragma unroll
  for (int nt = 4; nt < 8; ++nt) {                  // k
    float4 b4 = *(const float4*)(bq + 64 + (nt - 4) * 16 + 4 * g);
    half4v hv = {(f16)(acc[nt][0] + b4.x), (f16)(acc[nt][1] + b4.y),
                 (f16)(acc[nt][2] + b4.z), (f16)(acc[nt][3] + b4.w)};
    *(half4v*)(kh + grow * DHEAD + (nt - 4) * 16 + 4 * g) = hv;
  }
#pragma unroll
  for (int nt = 8; nt < 12; ++nt) {                 // v: D[seq=4g+r][d=qr]
    const int d = (nt - 8) * 16 + qr;
    const float bv = bq[128 + d];
    half4v hv = {(f16)(acc[nt][0] + bv), (f16)(acc[nt][1] + bv),
                 (f16)(acc[nt][2] + bv), (f16)(acc[nt][3] + bv)};
    *(half4v*)(vt + (size_t)bi * DHEAD * SEQ + (size_t)d * SEQ
               + seqb + w * 16 + 4 * g) = hv;
  }
  // ---- tail: blocks 0..15 emit W_out^T fp16 (wt[c][k]) ----
  if (blockIdx.x < 16) {
    const int gid = blockIdx.x * 256 + t;   // 0..4095
    const int c = gid & 255;
    const int k0 = (gid >> 8) * 4;          // 0..60
    half4v wv = {(f16)Wo[(size_t)(k0 + 0) * DMODEL + c],
                 (f16)Wo[(size_t)(k0 + 1) * DMODEL + c],
                 (f16)Wo[(size_t)(k0 + 2) * DMODEL + c],
                 (f16)Wo[(size_t)(k0 + 3) * DMODEL + c]};
    *(half4v*)(wt + (size_t)c * DHEAD + k0) = wv;
  }
}

// ---------------------------------------------------------------------------
// Kernel B: fused scores -> threshold -> masked softmax -> PV -> OUT PROJ.
// R19 = exact R15 structure (best verified: attn 87.5 us, total 100.6 us).
// Double-buffered global_load_lds staging, counted vmcnt(4), SCHED_PIN before
// in-loop stage issue, wave-local selection (shfl-only bisection), exp2,
// MFMA out-proj epilogue. Five stall-class experiments (barriers, pipeline
// depth, occupancy, setprio, direct-reg loads) landed null or negative —
// this is the structure's practical floor.
// ---------------------------------------------------------------------------
#define WAVES  8
#define CHUNK  32
#define NCHUNK 16
#define BUFH   2048    // halves per buffer (4 KB = 32 rows x 64 halves)

__device__ __forceinline__ int khash(int row) {   // bijective per permuted tile
  return ((row >> 2) & 6) | ((row >> 1) & 1);
}

typedef __attribute__((address_space(3))) f16 as3_f16;
typedef __attribute__((address_space(1))) const f16 as1_f16;

__device__ __forceinline__ void gll16(const f16* g, f16* l) {
  __builtin_amdgcn_global_load_lds((as1_f16*)g, (as3_f16*)l, 16, 0, 0);
}

#define SCHED_PIN __builtin_amdgcn_sched_barrier(0)
#define WAITVM4 do { asm volatile("s_waitcnt vmcnt(4)" ::: "memory"); \
                     __builtin_amdgcn_sched_barrier(0); } while (0)
#define WAITVM0 do { asm volatile("s_waitcnt vmcnt(0)" ::: "memory"); \
                     __builtin_amdgcn_sched_barrier(0); } while (0)

// K chunk -> LDS[row 0..31][slot 0..7], source slot pre-XOR'd with khash(row)
__device__ __forceinline__ void stage_k(const f16* kchunk, f16* buf, int l) {
#pragma unroll
  for (int i = 0; i < 4; ++i) {
    const int row = i * 8 + (l >> 3);
    const int c8 = (l & 7) ^ khash(row);
    gll16(kchunk + row * DHEAD + c8 * 8, buf + i * 512);
  }
}

// V chunk -> LDS rows = d&31 (128 B), slots 0..3 = d<32, 4..7 = d>=32, XOR r&7
__device__ __forceinline__ void stage_v(const f16* vchunk, f16* buf, int l) {
#pragma unroll
  for (int i = 0; i < 4; ++i) {
    const int r = i * 8 + (l >> 3);
    const int jj = (l & 7) ^ (r & 7);
    const int d = ((jj >> 2) << 5) + r;
    const int kb = jj & 3;
    gll16(vchunk + (size_t)d * SEQ + kb * 8, buf + i * 512);
  }
}

__global__ __launch_bounds__(512) void attn_fused(
    const f16* __restrict__ qh, const f16* __restrict__ kh,
    const f16* __restrict__ vt, const f16* __restrict__ wt,
    const float* __restrict__ bo, float* __restrict__ out)
{
  __shared__ f16 stage[WAVES][2 * BUFH];     // 64 KB: per-wave double buffer
  __shared__ float selbuf[WAVES][16];        // z cross-wave reduce only
  __shared__ float zrow[16];
  __shared__ float obuf[16 * 68];            // 4.35 KB: O rows (post-division)

  const int tid = threadIdx.x;
  const int w = tid >> 6;
  const int l = tid & 63;
  const int qr = l & 15;
  const int g  = l >> 4;
  const int bi = blockIdx.x >> 8;
  const int rb = blockIdx.x & 255;
  const size_t qrow0  = (size_t)bi * SEQ + (size_t)rb * 16;
  const size_t kvbase = (size_t)bi * SEQ * DHEAD;
  const int key0 = w * (CHUNK * NCHUNK);

  f16* const mybuf = &stage[w][0];

  // Q fragments (B operand), q pre-scaled by QSCALE in qh.
  half8 qf0, qf1;
  {
    const f16* qp = qh + (qrow0 + qr) * DHEAD;
    qf0 = *(const half8*)(qp + 8 * g);
    qf1 = *(const half8*)(qp + 32 + 8 * g);
  }

  half4v P[2 * NCHUNK];   // P[2kc+kt][r] = S[qr][32kc + 8g + 4kt + r] (log2 dom.)
  float mn = 1e30f, mx = -1e30f;

  // ---- QK^T: async pipeline, no barriers ----
  const f16* kc0 = kh + kvbase + (size_t)key0 * DHEAD;
  stage_k(kc0, mybuf, l);
  stage_k(kc0 + 32 * DHEAD, mybuf + BUFH, l);
#pragma unroll
  for (int kc = 0; kc < NCHUNK; ++kc) {
    if (kc < NCHUNK - 1) { WAITVM4; } else { WAITVM0; }
    const f16* bufp = mybuf + (kc & 1) * BUFH;
#pragma unroll
    for (int kt = 0; kt < 2; ++kt) {
      const int rowk = 8 * (qr >> 2) + 4 * kt + (qr & 3);   // permuted key row
      const int h = khash(rowk);
      f32x4 c = {0.f, 0.f, 0.f, 0.f};
      half8 kf0 = *(const half8*)(bufp + rowk * DHEAD + ((g ^ h) * 8));
      c = __builtin_amdgcn_mfma_f32_16x16x32_f16(kf0, qf0, c, 0, 0, 0);
      half8 kf1 = *(const half8*)(bufp + rowk * DHEAD + (((4 + g) ^ h) * 8));
      c = __builtin_amdgcn_mfma_f32_16x16x32_f16(kf1, qf1, c, 0, 0, 0);
      mn = fminf(mn, fminf(fminf(c[0], c[1]), fminf(c[2], c[3])));
      mx = fmaxf(mx, fmaxf(fmaxf(c[0], c[1]), fmaxf(c[2], c[3])));
      P[kc * 2 + kt] = (half4v){(f16)c[0], (f16)c[1], (f16)c[2], (f16)c[3]};
    }
    if (kc + 2 < NCHUNK) {
      SCHED_PIN;   // all reads of buf[kc&1] complete (in-order DS) before DMA
      stage_k(kc0 + (size_t)(kc + 2) * 32 * DHEAD, mybuf + (kc & 1) * BUFH, l);
    }
  }

  // ---- WAVE-LOCAL selection: row min/max across the row's 4 lanes ----
  mn = fminf(mn, __shfl_xor(mn, 16, 64));
  mn = fminf(mn, __shfl_xor(mn, 32, 64));
  mx = fmaxf(mx, __shfl_xor(mx, 16, 64));
  mx = fmaxf(mx, __shfl_xor(mx, 32, 64));
  float lo = mn, hi = mx;

  // ---- wave-local bisection: 128 samples/row (32/lane), target 64 ----
#pragma unroll
  for (int it = 0; it < 10; ++it) {
    const float tm = 0.5f * (lo + hi);
    const f16 th = (f16)tm;
    int cnt = 0;
#pragma unroll
    for (int j = 0; j < 2 * NCHUNK; j += 4) {
      half4v s = P[j];
      cnt += (s[0] >= th) + (s[1] >= th) + (s[2] >= th) + (s[3] >= th);
    }
    cnt += __shfl_xor(cnt, 16, 64);
    cnt += __shfl_xor(cnt, 32, 64);
    if (cnt >= 64) lo = tm; else hi = tm;
  }
  const float thr = lo;

  // ---- prefetch V chunks 0/1 (exp loop hides the latency) ----
  SCHED_PIN;
  const f16* vchunk0 = vt + (size_t)bi * DHEAD * SEQ + key0;
  stage_v(vchunk0, mybuf, l);
  stage_v(vchunk0 + 32, mybuf + BUFH, l);

  // ---- exp2 in place (scores already in log2 domain; masked -> 1) ----
  float z = 0.f;
#pragma unroll
  for (int j = 0; j < 2 * NCHUNK; ++j) {
    half4v s = P[j];
    float p0 = (float)s[0], p1 = (float)s[1], p2 = (float)s[2], p3 = (float)s[3];
    p0 = (p0 >= thr) ? exp2f(p0) : 1.f;
    p1 = (p1 >= thr) ? exp2f(p1) : 1.f;
    p2 = (p2 >= thr) ? exp2f(p2) : 1.f;
    p3 = (p3 >= thr) ? exp2f(p3) : 1.f;
    z += (p0 + p1) + (p2 + p3);
    P[j] = (half4v){(f16)p0, (f16)p1, (f16)p2, (f16)p3};
  }
  z += __shfl_xor(z, 16, 64);
  z += __shfl_xor(z, 32, 64);
  if (l < 16) selbuf[w][l] = z;
  __syncthreads();
  if (w == 0 && l < 16) {
    float t2 = 0.f;
#pragma unroll
    for (int j = 0; j < WAVES; ++j) t2 += selbuf[j][l];
    zrow[l] = t2;   // consumed after the post-PV barrier
  }

  // ---- PV: O^T = V^T P^T; A = V^T (b128 LDS reads), B = P register concat ----
  f32x4 acc[4];
#pragma unroll
  for (int p = 0; p < 4; ++p) acc[p] = (f32x4){0.f, 0.f, 0.f, 0.f};

#pragma unroll
  for (int kc = 0; kc < NCHUNK; ++kc) {
    if (kc < NCHUNK - 1) { WAITVM4; } else { WAITVM0; }
    const f16* bufp = mybuf + (kc & 1) * BUFH;
    const half8 pb = __builtin_shufflevector(P[kc * 2], P[kc * 2 + 1],
                                             0, 1, 2, 3, 4, 5, 6, 7);
#pragma unroll
    for (int pnl = 0; pnl < 4; ++pnl) {
      const int d = 16 * pnl + qr;
      const int r = d & 31;
      const int j = (((d >> 5) << 2) + g) ^ (r & 7);
      half8 va = *(const half8*)(bufp + r * 64 + j * 8);
      acc[pnl] = __builtin_amdgcn_mfma_f32_16x16x32_f16(va, pb, acc[pnl], 0, 0, 0);
    }
    if (kc + 2 < NCHUNK) {
      SCHED_PIN;   // all reads of buf[kc&1] complete (in-order DS) before DMA
      stage_v(vchunk0 + (kc + 2) * 32, mybuf + (kc & 1) * BUFH, l);
    }
  }

  // ---- cross-wave reduce -> obuf (O/z), 68-pad rows ----
  float* red = (float*)mybuf;   // 16 rows x 68 floats = 4352 B per wave region
#pragma unroll
  for (int pnl = 0; pnl < 4; ++pnl)
    *(f32x4*)&red[qr * 68 + pnl * 16 + 4 * g] = acc[pnl];
  __syncthreads();
#pragma unroll
  for (int oo = 0; oo < 2; ++oo) {
    const int o = tid * 2 + oo;
    const int i = o >> 6, n = o & 63;
    float s = 0.f;
#pragma unroll
    for (int j = 0; j < WAVES; ++j) s += ((const float*)&stage[j][0])[i * 68 + n];
    obuf[i * 68 + n] = s / zrow[i];
  }
  __syncthreads();   // red reads done (stage reusable); obuf visible to all

  // ---- stage wt (W^T fp16) into stage[0..32KB]: wave w -> rows 32w..32w+31,
  // LDS linear, source block pre-XOR'd with (c&7) ----
  f16* const wl = &stage[0][0];
#pragma unroll
  for (int i = 0; i < 4; ++i) {
    const int c = (w * 4 + i) * 8 + (l >> 3);
    const int blk = (l & 7) ^ (c & 7);
    gll16(wt + (size_t)c * DHEAD + blk * 8, wl + (w * 4 + i) * 512);
  }
  WAITVM0;   // wave-local: wave w reads only rows it staged

  // ---- out = O @ W^T + bo via MFMA: wave w owns col tiles nt = 2w, 2w+1 ----
  half4v ofr[4];
#pragma unroll
  for (int pnl = 0; pnl < 4; ++pnl) {
    f32x4 o4 = *(const f32x4*)&obuf[qr * 68 + pnl * 16 + 4 * g];
    ofr[pnl] = (half4v){(f16)o4[0], (f16)o4[1], (f16)o4[2], (f16)o4[3]};
  }
#pragma unroll
  for (int nt2 = 0; nt2 < 2; ++nt2) {
    const int nt = w * 2 + nt2;
    const int c = 16 * nt + qr;             // output column
    const float bv = bo[c];
    f32x4 ao = {bv, bv, bv, bv};
#pragma unroll
    for (int pnl = 0; pnl < 4; ++pnl) {
      const int blk = 2 * pnl + (g >> 1);   // k-block = (16pnl+4g)>>3
      half4v wf = *(const half4v*)(wl + c * DHEAD + ((blk ^ (c & 7)) * 8) + (g & 1) * 4);
      ao = __builtin_amdgcn_mfma_f32_16x16x16f16(ofr[pnl], wf, ao, 0, 0, 0);
    }
    float* op = out + (qrow0 + 4 * g) * DMODEL + c;
#pragma unroll
    for (int r = 0; r < 4; ++r) op[r * DMODEL] = ao[r];
  }
}

// ---------------------------------------------------------------------------
extern "C" void kernel_launch(void* const* d_in, const int* in_sizes, int n_in,
                              void* d_out, int out_size, void* d_ws, size_t ws_size,
                              hipStream_t stream)
{
  (void)in_sizes; (void)n_in; (void)out_size; (void)ws_size;
  const float* x  = (const float*)d_in[0];
  const float* Wq = (const float*)d_in[1];
  const float* bq = (const float*)d_in[2];
  const float* Wo = (const float*)d_in[3];
  const float* bo = (const float*)d_in[4];
  float* out = (float*)d_out;
  char* ws = (char*)d_ws;
  f16* qh = (f16*)(ws);                              // 2 MB
  f16* kh = (f16*)(ws + (size_t)(2 << 20));          // 2 MB
  f16* vt = (f16*)(ws + (size_t)(4 << 20));          // 2 MB (transposed V)
  f16* wt = (f16*)(ws + (size_t)(6 << 20));          // 32 KB (W_out^T fp16)

  hipLaunchKernelGGL(qkv_mfma,   dim3(256),  dim3(256), 0, stream, x, Wq, bq, Wo, qh, kh, vt, wt);
  hipLaunchKernelGGL(attn_fused, dim3(1024), dim3(512), 0, stream, qh, kh, vt, wt, bo, out);
}